// Round 1
// baseline (550.889 us; speedup 1.0000x reference)
//
#include <hip/hip_runtime.h>

// SpatialGridProjector: out[b,q,j,i] = sum_k trilinear(density[b], P(i,j,k))
// P voxel coords: X(k) = Ax + k*R20, Y(k) = Ay + k*R21, Z(k) = Az + k*R22
// with Ax = 63.5*(lin_i*R00 + lin_j*R10 - R20 + 1), lin_t = -1 + t*(2/127).
// grid_sample(align_corners=True, zero padding) semantics: per-corner
// validity, clamped index gather, zero weight if out of range.

#define LSZ 128
#define QPOSE 8

__global__ __launch_bounds__(256) void proj_kernel(
    const float* __restrict__ density,   // (B, L, L, L)
    const float* __restrict__ rotation,  // (B, Q, 3, 3)
    float* __restrict__ out)             // (B, Q, L, L) ; out[((bq)*L + j)*L + i]
{
    const int tid = blockIdx.x * 256 + threadIdx.x;
    const int i  = tid & (LSZ - 1);
    const int j  = (tid >> 7) & (LSZ - 1);
    const int bq = tid >> 14;            // uniform within a block (64 blocks per image)
    const int b  = bq >> 3;

    const float* R = rotation + bq * 9;  // row-major (c, m): R[c*3 + m]
    const float R00 = R[0], R01 = R[1], R02 = R[2];
    const float R10 = R[3], R11 = R[4], R12 = R[5];
    const float R20 = R[6], R21 = R[7], R22 = R[8];

    const float step = 2.0f / 127.0f;
    const float li = -1.0f + (float)i * step;
    const float lj = -1.0f + (float)j * step;

    // voxel-space starting position (k = 0) and per-k step (= R[2][m])
    const float Ax = 63.5f * (li * R00 + lj * R10 - R20 + 1.0f);
    const float Ay = 63.5f * (li * R01 + lj * R11 - R21 + 1.0f);
    const float Az = 63.5f * (li * R02 + lj * R12 - R22 + 1.0f);

    const float* __restrict__ vol = density + (size_t)b * (LSZ * LSZ * LSZ);

    float acc = 0.0f;

    for (int k = 0; k < LSZ; ++k) {
        const float kf = (float)k;
        const float X = fmaf(kf, R20, Ax);
        const float Y = fmaf(kf, R21, Ay);
        const float Z = fmaf(kf, R22, Az);

        // entirely outside the sampling footprint on any axis -> contributes 0
        if (X <= -1.0f || X >= 128.0f ||
            Y <= -1.0f || Y >= 128.0f ||
            Z <= -1.0f || Z >= 128.0f) continue;

        const float xf = floorf(X), yf = floorf(Y), zf = floorf(Z);
        const int ix = (int)xf, iy = (int)yf, iz = (int)zf;   // each in [-1, 127]
        const float fx = X - xf, fy = Y - yf, fz = Z - zf;

        const bool vx0 = (ix >= 0);            // ix <= 127 guaranteed
        const bool vx1 = (ix <= 126);          // ix+1 valid
        const bool vy0 = (iy >= 0);
        const bool vy1 = (iy <= 126);
        const bool vz0 = (iz >= 0);
        const bool vz1 = (iz <= 126);

        const int cx0 = vx0 ? ix : 0;
        const int cx1 = vx1 ? ix + 1 : 127;
        const int cy0 = vy0 ? iy : 0;
        const int cy1 = vy1 ? iy + 1 : 127;
        const int cz0 = vz0 ? iz : 0;
        const int cz1 = vz1 ? iz + 1 : 127;

        const float gx0 = vx0 ? (1.0f - fx) : 0.0f;
        const float gx1 = vx1 ? fx : 0.0f;
        const float gy0 = vy0 ? (1.0f - fy) : 0.0f;
        const float gy1 = vy1 ? fy : 0.0f;
        const float gz0 = vz0 ? (1.0f - fz) : 0.0f;
        const float gz1 = vz1 ? fz : 0.0f;

        const int z0off = cz0 << 14, z1off = cz1 << 14;
        const int y0off = cy0 << 7,  y1off = cy1 << 7;

        const float v000 = vol[z0off + y0off + cx0];
        const float v100 = vol[z0off + y0off + cx1];
        const float v010 = vol[z0off + y1off + cx0];
        const float v110 = vol[z0off + y1off + cx1];
        const float v001 = vol[z1off + y0off + cx0];
        const float v101 = vol[z1off + y0off + cx1];
        const float v011 = vol[z1off + y1off + cx0];
        const float v111 = vol[z1off + y1off + cx1];

        const float s0 = gy0 * fmaf(gx0, v000, gx1 * v100)
                       + gy1 * fmaf(gx0, v010, gx1 * v110);
        const float s1 = gy0 * fmaf(gx0, v001, gx1 * v101)
                       + gy1 * fmaf(gx0, v011, gx1 * v111);
        acc = fmaf(gz0, s0, fmaf(gz1, s1, acc));
    }

    out[tid] = acc;
}

extern "C" void kernel_launch(void* const* d_in, const int* in_sizes, int n_in,
                              void* d_out, int out_size, void* d_ws, size_t ws_size,
                              hipStream_t stream) {
    const float* density  = (const float*)d_in[0];
    const float* rotation = (const float*)d_in[1];
    float* out = (float*)d_out;
    // B*Q*L*L = 4*8*128*128 = 524288 threads
    proj_kernel<<<2048, 256, 0, stream>>>(density, rotation, out);
}

// Round 2
// 489.086 us; speedup vs baseline: 1.1264x; 1.1264x over previous
//
#include <hip/hip_runtime.h>

// SpatialGridProjector: out[b,q,j,i] = sum_k trilinear(density[b], P(i,j,k))
// X(k) = Ax + k*R20, Y(k) = Ay + k*R21, Z(k) = Az + k*R22  (voxel coords)
// grid_sample(align_corners=True, zero padding): per-corner validity,
// clamped-index gather, zero weight out of range.
//
// R1 changes vs R0:
//  - analytic per-ray valid-k interval (branchless inner loop, unroll 4)
//  - XCD swizzle: volume b -> XCDs {2b, 2b+1} so each 4MiB L2 serves one volume

#define LSZ 128

__global__ __launch_bounds__(256) void proj_kernel(
    const float* __restrict__ density,   // (B, L, L, L)
    const float* __restrict__ rotation,  // (B, Q, 3, 3)
    float* __restrict__ out)             // (B, Q, L, L)
{
    // --- XCD-aware swizzle (blockIdx % 8 ~ XCD on MI355X; heuristic only) ---
    const int xcd  = blockIdx.x & 7;
    const int slot = blockIdx.x >> 3;          // 0..255
    const int b    = xcd >> 1;                 // volume 0..3
    const int tile = ((xcd & 1) << 8) + slot;  // 0..511 within volume
    const int q    = tile >> 6;                // 0..7
    const int blk  = tile & 63;                // block within image
    const int bq   = (b << 3) + q;

    const int p = (blk << 8) + threadIdx.x;    // pixel index in image, 0..16383
    const int i = p & (LSZ - 1);
    const int j = p >> 7;

    const float* R = rotation + bq * 9;        // R[c*3 + m]
    const float R00 = R[0], R01 = R[1], R02 = R[2];
    const float R10 = R[3], R11 = R[4], R12 = R[5];
    const float R20 = R[6], R21 = R[7], R22 = R[8];

    const float step = 2.0f / 127.0f;
    const float li = -1.0f + (float)i * step;
    const float lj = -1.0f + (float)j * step;

    // voxel-space start (k=0) and per-k step (= R[2][m] exactly, 63.5*2/127=1)
    const float Ax = 63.5f * (li * R00 + lj * R10 - R20 + 1.0f);
    const float Ay = 63.5f * (li * R01 + lj * R11 - R21 + 1.0f);
    const float Az = 63.5f * (li * R02 + lj * R12 - R22 + 1.0f);

    // --- analytic valid-k interval: Ax + k*s in (-1, 128) for each axis ---
    float klo = 0.0f, khi = 127.0f;
    bool empty = false;
    {
        const float a[3] = {Ax, Ay, Az};
        const float s[3] = {R20, R21, R22};
        #pragma unroll
        for (int m = 0; m < 3; ++m) {
            if (fabsf(s[m]) > 1e-6f) {
                const float t0 = (-1.0f  - a[m]) / s[m];
                const float t1 = (128.0f - a[m]) / s[m];
                klo = fmaxf(klo, fminf(t0, t1));
                khi = fminf(khi, fmaxf(t0, t1));
            } else if (a[m] <= -1.0f || a[m] >= 128.0f) {
                empty = true;
            }
        }
    }
    int k_start = (int)ceilf(klo - 1e-3f);
    int k_end   = (int)floorf(khi + 1e-3f);
    if (k_start < 0) k_start = 0;
    if (k_end > 127) k_end = 127;
    if (empty) k_end = k_start - 1;

    const float* __restrict__ vol = density + (size_t)b * (LSZ * LSZ * LSZ);

    float acc = 0.0f;

    #pragma unroll 4
    for (int k = k_start; k <= k_end; ++k) {
        const float kf = (float)k;
        const float X = fmaf(kf, R20, Ax);
        const float Y = fmaf(kf, R21, Ay);
        const float Z = fmaf(kf, R22, Az);

        const float xf = floorf(X), yf = floorf(Y), zf = floorf(Z);
        const int ix = (int)xf, iy = (int)yf, iz = (int)zf;
        const float fx = X - xf, fy = Y - yf, fz = Z - zf;

        // per-corner validity (interval slop handled here; fully branchless)
        const bool vx0 = (ix >= 0)  & (ix <= 127);
        const bool vx1 = (ix >= -1) & (ix <= 126);
        const bool vy0 = (iy >= 0)  & (iy <= 127);
        const bool vy1 = (iy >= -1) & (iy <= 126);
        const bool vz0 = (iz >= 0)  & (iz <= 127);
        const bool vz1 = (iz >= -1) & (iz <= 126);

        const int cx0 = min(max(ix, 0), 127);
        const int cx1 = min(max(ix + 1, 0), 127);
        const int cy0 = min(max(iy, 0), 127);
        const int cy1 = min(max(iy + 1, 0), 127);
        const int cz0 = min(max(iz, 0), 127);
        const int cz1 = min(max(iz + 1, 0), 127);

        const float gx0 = vx0 ? (1.0f - fx) : 0.0f;
        const float gx1 = vx1 ? fx : 0.0f;
        const float gy0 = vy0 ? (1.0f - fy) : 0.0f;
        const float gy1 = vy1 ? fy : 0.0f;
        const float gz0 = vz0 ? (1.0f - fz) : 0.0f;
        const float gz1 = vz1 ? fz : 0.0f;

        const int z0off = cz0 << 14, z1off = cz1 << 14;
        const int y0off = cy0 << 7,  y1off = cy1 << 7;

        const float v000 = vol[z0off + y0off + cx0];
        const float v100 = vol[z0off + y0off + cx1];
        const float v010 = vol[z0off + y1off + cx0];
        const float v110 = vol[z0off + y1off + cx1];
        const float v001 = vol[z1off + y0off + cx0];
        const float v101 = vol[z1off + y0off + cx1];
        const float v011 = vol[z1off + y1off + cx0];
        const float v111 = vol[z1off + y1off + cx1];

        const float s0 = gy0 * fmaf(gx0, v000, gx1 * v100)
                       + gy1 * fmaf(gx0, v010, gx1 * v110);
        const float s1 = gy0 * fmaf(gx0, v001, gx1 * v101)
                       + gy1 * fmaf(gx0, v011, gx1 * v111);
        acc = fmaf(gz0, s0, fmaf(gz1, s1, acc));
    }

    out[(bq << 14) + p] = acc;
}

extern "C" void kernel_launch(void* const* d_in, const int* in_sizes, int n_in,
                              void* d_out, int out_size, void* d_ws, size_t ws_size,
                              hipStream_t stream) {
    const float* density  = (const float*)d_in[0];
    const float* rotation = (const float*)d_in[1];
    float* out = (float*)d_out;
    proj_kernel<<<2048, 256, 0, stream>>>(density, rotation, out);
}

// Round 3
// 389.263 us; speedup vs baseline: 1.4152x; 1.2564x over previous
//
#include <hip/hip_runtime.h>

// SpatialGridProjector: out[b,q,j,i] = sum_k trilinear(density[b], P(i,j,k))
// X(k) = Ax + k*R20, Y(k) = Ay + k*R21, Z(k) = Az + k*R22  (voxel coords)
// grid_sample(align_corners=True, zero padding).
//
// R2 changes vs R1:
//  - hand-written 2-stage software pipeline (ping-pong A/B register sets):
//    gathers for step k+1 are issued before step k's values are consumed,
//    doubling outstanding loads per thread (8 -> 16). R1 profile showed
//    gather-latency bound (VALUBusy 18%, HBM 2%, ~420 cy per wave-iteration).

#define LSZ 128

// Compute addresses+weights for step kk and ISSUE the 8 gathers into vS0..vS7.
#define PREP(S, kk) do {                                                      \
    const float kf_ = (float)(kk);                                            \
    const float X_ = fmaf(kf_, R20, Ax);                                      \
    const float Y_ = fmaf(kf_, R21, Ay);                                      \
    const float Z_ = fmaf(kf_, R22, Az);                                      \
    const float xf_ = floorf(X_), yf_ = floorf(Y_), zf_ = floorf(Z_);         \
    const int ix_ = (int)xf_, iy_ = (int)yf_, iz_ = (int)zf_;                 \
    const float fx_ = X_ - xf_, fy_ = Y_ - yf_, fz_ = Z_ - zf_;               \
    const bool vx0_ = (ix_ >= 0)  & (ix_ <= 127);                             \
    const bool vx1_ = (ix_ >= -1) & (ix_ <= 126);                             \
    const bool vy0_ = (iy_ >= 0)  & (iy_ <= 127);                             \
    const bool vy1_ = (iy_ >= -1) & (iy_ <= 126);                             \
    const bool vz0_ = (iz_ >= 0)  & (iz_ <= 127);                             \
    const bool vz1_ = (iz_ >= -1) & (iz_ <= 126);                             \
    const int cx0_ = min(max(ix_, 0), 127);                                   \
    const int cx1_ = min(max(ix_ + 1, 0), 127);                               \
    const int cy0_ = min(max(iy_, 0), 127);                                   \
    const int cy1_ = min(max(iy_ + 1, 0), 127);                               \
    const int cz0_ = min(max(iz_, 0), 127);                                   \
    const int cz1_ = min(max(iz_ + 1, 0), 127);                               \
    g##S##x0 = vx0_ ? (1.0f - fx_) : 0.0f;                                    \
    g##S##x1 = vx1_ ? fx_ : 0.0f;                                             \
    g##S##y0 = vy0_ ? (1.0f - fy_) : 0.0f;                                    \
    g##S##y1 = vy1_ ? fy_ : 0.0f;                                             \
    g##S##z0 = vz0_ ? (1.0f - fz_) : 0.0f;                                    \
    g##S##z1 = vz1_ ? fz_ : 0.0f;                                             \
    const int z0o_ = cz0_ << 14, z1o_ = cz1_ << 14;                           \
    const int y0o_ = cy0_ << 7,  y1o_ = cy1_ << 7;                            \
    v##S##0 = vol[z0o_ + y0o_ + cx0_];                                        \
    v##S##1 = vol[z0o_ + y0o_ + cx1_];                                        \
    v##S##2 = vol[z0o_ + y1o_ + cx0_];                                        \
    v##S##3 = vol[z0o_ + y1o_ + cx1_];                                        \
    v##S##4 = vol[z1o_ + y0o_ + cx0_];                                        \
    v##S##5 = vol[z1o_ + y0o_ + cx1_];                                        \
    v##S##6 = vol[z1o_ + y1o_ + cx0_];                                        \
    v##S##7 = vol[z1o_ + y1o_ + cx1_];                                        \
} while (0)

#define CONSUME(S) do {                                                       \
    const float s0_ = g##S##y0 * fmaf(g##S##x0, v##S##0, g##S##x1 * v##S##1)  \
                    + g##S##y1 * fmaf(g##S##x0, v##S##2, g##S##x1 * v##S##3); \
    const float s1_ = g##S##y0 * fmaf(g##S##x0, v##S##4, g##S##x1 * v##S##5)  \
                    + g##S##y1 * fmaf(g##S##x0, v##S##6, g##S##x1 * v##S##7); \
    acc = fmaf(g##S##z0, s0_, fmaf(g##S##z1, s1_, acc));                      \
} while (0)

__global__ __launch_bounds__(256) void proj_kernel(
    const float* __restrict__ density,   // (B, L, L, L)
    const float* __restrict__ rotation,  // (B, Q, 3, 3)
    float* __restrict__ out)             // (B, Q, L, L)
{
    // XCD-aware swizzle: volume b -> XCDs {2b, 2b+1} (blockIdx % 8 ~ XCD).
    const int xcd  = blockIdx.x & 7;
    const int slot = blockIdx.x >> 3;          // 0..255
    const int b    = xcd >> 1;                 // volume 0..3
    const int tile = ((xcd & 1) << 8) + slot;  // 0..511 within volume
    const int q    = tile >> 6;                // 0..7
    const int blk  = tile & 63;
    const int bq   = (b << 3) + q;

    const int p = (blk << 8) + threadIdx.x;    // pixel in image, 0..16383
    const int i = p & (LSZ - 1);
    const int j = p >> 7;

    const float* R = rotation + bq * 9;        // R[c*3 + m]
    const float R00 = R[0], R01 = R[1], R02 = R[2];
    const float R10 = R[3], R11 = R[4], R12 = R[5];
    const float R20 = R[6], R21 = R[7], R22 = R[8];

    const float step = 2.0f / 127.0f;
    const float li = -1.0f + (float)i * step;
    const float lj = -1.0f + (float)j * step;

    const float Ax = 63.5f * (li * R00 + lj * R10 - R20 + 1.0f);
    const float Ay = 63.5f * (li * R01 + lj * R11 - R21 + 1.0f);
    const float Az = 63.5f * (li * R02 + lj * R12 - R22 + 1.0f);

    // analytic valid-k interval: A + k*s in (-1, 128) per axis
    float klo = 0.0f, khi = 127.0f;
    bool empty = false;
    {
        const float a[3] = {Ax, Ay, Az};
        const float s[3] = {R20, R21, R22};
        #pragma unroll
        for (int m = 0; m < 3; ++m) {
            if (fabsf(s[m]) > 1e-6f) {
                const float t0 = (-1.0f  - a[m]) / s[m];
                const float t1 = (128.0f - a[m]) / s[m];
                klo = fmaxf(klo, fminf(t0, t1));
                khi = fminf(khi, fmaxf(t0, t1));
            } else if (a[m] <= -1.0f || a[m] >= 128.0f) {
                empty = true;
            }
        }
    }
    int k_start = (int)ceilf(klo - 1e-3f);
    int k_end   = (int)floorf(khi + 1e-3f);
    if (k_start < 0) k_start = 0;
    if (k_end > 127) k_end = 127;
    if (empty) k_end = k_start - 1;

    const float* __restrict__ vol = density + (size_t)b * (LSZ * LSZ * LSZ);

    float acc = 0.0f;

    // ping-pong pipeline registers
    float gAx0, gAx1, gAy0, gAy1, gAz0, gAz1;
    float vA0, vA1, vA2, vA3, vA4, vA5, vA6, vA7;
    float gBx0, gBx1, gBy0, gBy1, gBz0, gBz1;
    float vB0, vB1, vB2, vB3, vB4, vB5, vB6, vB7;

    int k = k_start;
    if (k <= k_end) {
        PREP(A, k);
        while (k <= k_end) {
            const int kn = k + 1;
            const bool hasB = (kn <= k_end);
            if (hasB) PREP(B, kn);   // B's gathers in flight before A consumed
            CONSUME(A);
            if (hasB) CONSUME(B);
            k += 2;
            if (k <= k_end) PREP(A, k);  // next A in flight before loop back
        }
    }

    out[(bq << 14) + p] = acc;
}

extern "C" void kernel_launch(void* const* d_in, const int* in_sizes, int n_in,
                              void* d_out, int out_size, void* d_ws, size_t ws_size,
                              hipStream_t stream) {
    const float* density  = (const float*)d_in[0];
    const float* rotation = (const float*)d_in[1];
    float* out = (float*)d_out;
    proj_kernel<<<2048, 256, 0, stream>>>(density, rotation, out);
}

// Round 5
// 358.431 us; speedup vs baseline: 1.5369x; 1.0860x over previous
//
#include <hip/hip_runtime.h>

// SpatialGridProjector: out[b,q,j,i] = sum_k trilinear(density[b], P(i,j,k))
// X(k) = Ax + k*R20, Y(k) = Ay + k*R21, Z(k) = Az + k*R22  (voxel coords)
// grid_sample(align_corners=True, zero padding).
//
// R4 = R3 with the macro token-pasting bug fixed (pair regs renamed to
// letters: p##S##a etc. — `p##S##00.y` lexed `00.y` as a float literal).
//
// R3 changes vs R2:
//  - x-adjacent corner pairs fetched as ONE global_load_dwordx2 (align 4):
//    8 gathers/step -> 4, halving L1 line requests (R2 was mem-issue bound).
//  - boundary clamp via load at ex=clamp(ix,0,126) + per-corner select;
//    invalid corners already get zero weight.

#define LSZ 128

typedef float f2 __attribute__((ext_vector_type(2), aligned(4)));

// Compute weights for step kk and ISSUE the 4 pair-gathers.
#define PREP(S, kk) do {                                                      \
    const float kf_ = (float)(kk);                                            \
    const float X_ = fmaf(kf_, R20, Ax);                                      \
    const float Y_ = fmaf(kf_, R21, Ay);                                      \
    const float Z_ = fmaf(kf_, R22, Az);                                      \
    const float xf_ = floorf(X_), yf_ = floorf(Y_), zf_ = floorf(Z_);         \
    const int ix_ = (int)xf_, iy_ = (int)yf_, iz_ = (int)zf_;                 \
    const float fx_ = X_ - xf_, fy_ = Y_ - yf_, fz_ = Z_ - zf_;               \
    const bool vx0_ = (ix_ >= 0)  & (ix_ <= 127);                             \
    const bool vx1_ = (ix_ >= -1) & (ix_ <= 126);                             \
    const bool vy0_ = (iy_ >= 0)  & (iy_ <= 127);                             \
    const bool vy1_ = (iy_ >= -1) & (iy_ <= 126);                             \
    const bool vz0_ = (iz_ >= 0)  & (iz_ <= 127);                             \
    const bool vz1_ = (iz_ >= -1) & (iz_ <= 126);                             \
    const int ex_  = min(max(ix_, 0), 126);                                   \
    s##S##hi = (ix_ > 126);                                                   \
    s##S##lo = (ix_ < 0);                                                     \
    const int cy0_ = min(max(iy_, 0), 127);                                   \
    const int cy1_ = min(max(iy_ + 1, 0), 127);                               \
    const int cz0_ = min(max(iz_, 0), 127);                                   \
    const int cz1_ = min(max(iz_ + 1, 0), 127);                               \
    g##S##x0 = vx0_ ? (1.0f - fx_) : 0.0f;                                    \
    g##S##x1 = vx1_ ? fx_ : 0.0f;                                             \
    g##S##y0 = vy0_ ? (1.0f - fy_) : 0.0f;                                    \
    g##S##y1 = vy1_ ? fy_ : 0.0f;                                             \
    g##S##z0 = vz0_ ? (1.0f - fz_) : 0.0f;                                    \
    g##S##z1 = vz1_ ? fz_ : 0.0f;                                             \
    const int z0o_ = cz0_ << 14, z1o_ = cz1_ << 14;                           \
    const int y0o_ = cy0_ << 7,  y1o_ = cy1_ << 7;                            \
    p##S##a = *(const f2*)(vol + (z0o_ + y0o_ + ex_));                        \
    p##S##b = *(const f2*)(vol + (z0o_ + y1o_ + ex_));                        \
    p##S##c = *(const f2*)(vol + (z1o_ + y0o_ + ex_));                        \
    p##S##d = *(const f2*)(vol + (z1o_ + y1o_ + ex_));                        \
} while (0)

// Resolve clamp-edge selects and fold the trilinear reduce into acc.
#define CONSUME(S) do {                                                       \
    const float c000 = s##S##hi ? p##S##a.y : p##S##a.x;                      \
    const float c100 = s##S##lo ? p##S##a.x : p##S##a.y;                      \
    const float c010 = s##S##hi ? p##S##b.y : p##S##b.x;                      \
    const float c110 = s##S##lo ? p##S##b.x : p##S##b.y;                      \
    const float c001 = s##S##hi ? p##S##c.y : p##S##c.x;                      \
    const float c101 = s##S##lo ? p##S##c.x : p##S##c.y;                      \
    const float c011 = s##S##hi ? p##S##d.y : p##S##d.x;                      \
    const float c111 = s##S##lo ? p##S##d.x : p##S##d.y;                      \
    const float s0_ = g##S##y0 * fmaf(g##S##x0, c000, g##S##x1 * c100)        \
                    + g##S##y1 * fmaf(g##S##x0, c010, g##S##x1 * c110);       \
    const float s1_ = g##S##y0 * fmaf(g##S##x0, c001, g##S##x1 * c101)        \
                    + g##S##y1 * fmaf(g##S##x0, c011, g##S##x1 * c111);       \
    acc = fmaf(g##S##z0, s0_, fmaf(g##S##z1, s1_, acc));                      \
} while (0)

__global__ __launch_bounds__(256) void proj_kernel(
    const float* __restrict__ density,   // (B, L, L, L)
    const float* __restrict__ rotation,  // (B, Q, 3, 3)
    float* __restrict__ out)             // (B, Q, L, L)
{
    // XCD-aware swizzle: volume b -> XCDs {2b, 2b+1} (blockIdx % 8 ~ XCD).
    const int xcd  = blockIdx.x & 7;
    const int slot = blockIdx.x >> 3;          // 0..255
    const int b    = xcd >> 1;                 // volume 0..3
    const int tile = ((xcd & 1) << 8) + slot;  // 0..511 within volume
    const int q    = tile >> 6;                // 0..7
    const int blk  = tile & 63;
    const int bq   = (b << 3) + q;

    const int p = (blk << 8) + threadIdx.x;    // pixel in image, 0..16383
    const int i = p & (LSZ - 1);
    const int j = p >> 7;

    const float* R = rotation + bq * 9;        // R[c*3 + m]
    const float R00 = R[0], R01 = R[1], R02 = R[2];
    const float R10 = R[3], R11 = R[4], R12 = R[5];
    const float R20 = R[6], R21 = R[7], R22 = R[8];

    const float step = 2.0f / 127.0f;
    const float li = -1.0f + (float)i * step;
    const float lj = -1.0f + (float)j * step;

    const float Ax = 63.5f * (li * R00 + lj * R10 - R20 + 1.0f);
    const float Ay = 63.5f * (li * R01 + lj * R11 - R21 + 1.0f);
    const float Az = 63.5f * (li * R02 + lj * R12 - R22 + 1.0f);

    // analytic valid-k interval: A + k*s in (-1, 128) per axis
    float klo = 0.0f, khi = 127.0f;
    bool empty = false;
    {
        const float a[3] = {Ax, Ay, Az};
        const float s[3] = {R20, R21, R22};
        #pragma unroll
        for (int m = 0; m < 3; ++m) {
            if (fabsf(s[m]) > 1e-6f) {
                const float t0 = (-1.0f  - a[m]) / s[m];
                const float t1 = (128.0f - a[m]) / s[m];
                klo = fmaxf(klo, fminf(t0, t1));
                khi = fminf(khi, fmaxf(t0, t1));
            } else if (a[m] <= -1.0f || a[m] >= 128.0f) {
                empty = true;
            }
        }
    }
    int k_start = (int)ceilf(klo - 1e-3f);
    int k_end   = (int)floorf(khi + 1e-3f);
    if (k_start < 0) k_start = 0;
    if (k_end > 127) k_end = 127;
    if (empty) k_end = k_start - 1;

    const float* __restrict__ vol = density + (size_t)b * (LSZ * LSZ * LSZ);

    float acc = 0.0f;

    // ping-pong pipeline registers
    float gAx0, gAx1, gAy0, gAy1, gAz0, gAz1;
    f2 pAa, pAb, pAc, pAd;
    bool sAhi, sAlo;
    float gBx0, gBx1, gBy0, gBy1, gBz0, gBz1;
    f2 pBa, pBb, pBc, pBd;
    bool sBhi, sBlo;

    int k = k_start;
    if (k <= k_end) {
        PREP(A, k);
        while (k <= k_end) {
            const int kn = k + 1;
            const bool hasB = (kn <= k_end);
            if (hasB) PREP(B, kn);   // B's gathers in flight before A consumed
            CONSUME(A);
            if (hasB) CONSUME(B);
            k += 2;
            if (k <= k_end) PREP(A, k);  // next A in flight before loop back
        }
    }

    out[(bq << 14) + p] = acc;
}

extern "C" void kernel_launch(void* const* d_in, const int* in_sizes, int n_in,
                              void* d_out, int out_size, void* d_ws, size_t ws_size,
                              hipStream_t stream) {
    const float* density  = (const float*)d_in[0];
    const float* rotation = (const float*)d_in[1];
    float* out = (float*)d_out;
    proj_kernel<<<2048, 256, 0, stream>>>(density, rotation, out);
}

// Round 6
// 218.011 us; speedup vs baseline: 2.5269x; 1.6441x over previous
//
#include <hip/hip_runtime.h>

// SpatialGridProjector: out[b,q,j,i] = sum_k trilinear(density[b], P(i,j,k))
// X(k) = Ax + k*R20, Y(k) = Ay + k*R21, Z(k) = Az + k*R22  (voxel coords)
// grid_sample(align_corners=True, zero padding).
//
// R5: corner-packed bf16 volume in d_ws. Entry (z,y,x) = 4 bf16:
//   dword0 = { v(z,  y,x) | v(z,  y+1,x)<<16 }   (z-slab 0, y-pair)
//   dword1 = { v(z+1,y,x) | v(z+1,y+1,x)<<16 }   (z-slab 1, y-pair)
// One dwordx4 at (ez,ey,ex) covers entries ex,ex+1 -> ALL 8 corners in one
// 16B gather (R4 was L2->L1 line-transfer bound at 12.5% line utilization;
// this cuts gathers/step 4 -> 1 and lifts bytes-used-per-line ~3x).
// Edge clamp via per-axis lo/hi slot selects; invalid corners get zero weight.
// 4-stage pipeline; stage state = one 16B reg quad (weights recomputed).

#define LSZ 128
#define PACKED_BYTES ((size_t)4 * 128 * 128 * 128 * 8)  // 64 MiB

typedef float f2 __attribute__((ext_vector_type(2), aligned(4)));
typedef unsigned int u4v __attribute__((ext_vector_type(4), aligned(8)));

__device__ __forceinline__ float bl(unsigned int d) {
    return __uint_as_float(d << 16);
}
__device__ __forceinline__ float bh(unsigned int d) {
    return __uint_as_float(d & 0xffff0000u);
}

// ---------------- pack kernel: f32 volume -> corner-packed bf16 -------------
__device__ __forceinline__ unsigned int pk2(float lo, float hi) {
    unsigned int ul = __float_as_uint(lo), uh = __float_as_uint(hi);
    ul = (ul + 0x7fffu + ((ul >> 16) & 1u)) >> 16;   // RNE bf16
    uh = (uh + 0x7fffu + ((uh >> 16) & 1u)) >> 16;
    return ul | (uh << 16);
}

__global__ __launch_bounds__(128) void pack_kernel(
    const float* __restrict__ density, uint2* __restrict__ packed)
{
    const int x = threadIdx.x;
    const int y = blockIdx.x & 127;
    const int z = (blockIdx.x >> 7) & 127;
    const int b = blockIdx.x >> 14;
    const float* __restrict__ v = density + ((size_t)b << 21);
    const int y1 = min(y + 1, 127), z1 = min(z + 1, 127);
    const float vz0y0 = v[(z  << 14) + (y  << 7) + x];
    const float vz0y1 = v[(z  << 14) + (y1 << 7) + x];
    const float vz1y0 = v[(z1 << 14) + (y  << 7) + x];
    const float vz1y1 = v[(z1 << 14) + (y1 << 7) + x];
    packed[((size_t)b << 21) + (z << 14) + (y << 7) + x] =
        make_uint2(pk2(vz0y0, vz0y1), pk2(vz1y0, vz1y1));
}

// ---------------- main kernel (packed path) ---------------------------------
#define PREP(S, kk) do {                                                      \
    const float kf_ = (float)(kk);                                            \
    const float X_ = fmaf(kf_, R20, Ax);                                      \
    const float Y_ = fmaf(kf_, R21, Ay);                                      \
    const float Z_ = fmaf(kf_, R22, Az);                                      \
    const int ix_ = (int)floorf(X_);                                          \
    const int iy_ = (int)floorf(Y_);                                          \
    const int iz_ = (int)floorf(Z_);                                          \
    const int ex_ = min(max(ix_, 0), 126);                                    \
    const int ey_ = min(max(iy_, 0), 126);                                    \
    const int ez_ = min(max(iz_, 0), 126);                                    \
    u##S = *(const u4v*)(vol2 + ((ez_ << 14) + (ey_ << 7) + ex_));            \
} while (0)

#define CONSUME(S, kk) do {                                                   \
    const float kf_ = (float)(kk);                                            \
    const float X_ = fmaf(kf_, R20, Ax);                                      \
    const float Y_ = fmaf(kf_, R21, Ay);                                      \
    const float Z_ = fmaf(kf_, R22, Az);                                      \
    const float xf_ = floorf(X_), yf_ = floorf(Y_), zf_ = floorf(Z_);         \
    const int ix_ = (int)xf_, iy_ = (int)yf_, iz_ = (int)zf_;                 \
    const float fx_ = X_ - xf_, fy_ = Y_ - yf_, fz_ = Z_ - zf_;               \
    const bool vx0_ = (ix_ >= 0)  & (ix_ <= 127);                             \
    const bool vx1_ = (ix_ >= -1) & (ix_ <= 126);                             \
    const bool vy0_ = (iy_ >= 0)  & (iy_ <= 127);                             \
    const bool vy1_ = (iy_ >= -1) & (iy_ <= 126);                             \
    const bool vz0_ = (iz_ >= 0)  & (iz_ <= 127);                             \
    const bool vz1_ = (iz_ >= -1) & (iz_ <= 126);                             \
    const float gx0 = vx0_ ? (1.0f - fx_) : 0.0f;                             \
    const float gx1 = vx1_ ? fx_ : 0.0f;                                      \
    const float gy0 = vy0_ ? (1.0f - fy_) : 0.0f;                             \
    const float gy1 = vy1_ ? fy_ : 0.0f;                                      \
    const float gz0 = vz0_ ? (1.0f - fz_) : 0.0f;                             \
    const float gz1 = vz1_ ? fz_ : 0.0f;                                      \
    const bool xhi_ = (ix_ > 126), xlo_ = (ix_ < 0);                          \
    const bool yhi_ = (iy_ > 126), ylo_ = (iy_ < 0);                          \
    const bool zhi_ = (iz_ > 126), zlo_ = (iz_ < 0);                          \
    const unsigned int a0z0 = xhi_ ? u##S.z : u##S.x;                         \
    const unsigned int a0z1 = xhi_ ? u##S.w : u##S.y;                         \
    const unsigned int a1z0 = xlo_ ? u##S.x : u##S.z;                         \
    const unsigned int a1z1 = xlo_ ? u##S.y : u##S.w;                         \
    const unsigned int dA = zhi_ ? a0z1 : a0z0;  /* (x0, z0) y-pair */        \
    const unsigned int dB = zlo_ ? a0z0 : a0z1;  /* (x0, z1) y-pair */        \
    const unsigned int dC = zhi_ ? a1z1 : a1z0;  /* (x1, z0) y-pair */        \
    const unsigned int dD = zlo_ ? a1z0 : a1z1;  /* (x1, z1) y-pair */        \
    const float c000 = yhi_ ? bh(dA) : bl(dA);                                \
    const float c010 = ylo_ ? bl(dA) : bh(dA);                                \
    const float c100 = yhi_ ? bh(dC) : bl(dC);                                \
    const float c110 = ylo_ ? bl(dC) : bh(dC);                                \
    const float c001 = yhi_ ? bh(dB) : bl(dB);                                \
    const float c011 = ylo_ ? bl(dB) : bh(dB);                                \
    const float c101 = yhi_ ? bh(dD) : bl(dD);                                \
    const float c111 = ylo_ ? bl(dD) : bh(dD);                                \
    const float s0_ = gy0 * fmaf(gx0, c000, gx1 * c100)                       \
                    + gy1 * fmaf(gx0, c010, gx1 * c110);                      \
    const float s1_ = gy0 * fmaf(gx0, c001, gx1 * c101)                       \
                    + gy1 * fmaf(gx0, c011, gx1 * c111);                      \
    acc = fmaf(gz0, s0_, fmaf(gz1, s1_, acc));                                \
} while (0)

__global__ __launch_bounds__(256) void proj_kernel_packed(
    const uint2* __restrict__ packed,    // (B, L, L, L) corner-packed bf16
    const float* __restrict__ rotation,  // (B, Q, 3, 3)
    float* __restrict__ out)             // (B, Q, L, L)
{
    // XCD-aware swizzle: volume b -> XCDs {2b, 2b+1} (blockIdx % 8 ~ XCD).
    const int xcd  = blockIdx.x & 7;
    const int slot = blockIdx.x >> 3;
    const int b    = xcd >> 1;
    const int tile = ((xcd & 1) << 8) + slot;
    const int q    = tile >> 6;
    const int blk  = tile & 63;
    const int bq   = (b << 3) + q;

    const int p = (blk << 8) + threadIdx.x;
    const int i = p & (LSZ - 1);
    const int j = p >> 7;

    const float* R = rotation + bq * 9;
    const float R00 = R[0], R01 = R[1], R02 = R[2];
    const float R10 = R[3], R11 = R[4], R12 = R[5];
    const float R20 = R[6], R21 = R[7], R22 = R[8];

    const float step = 2.0f / 127.0f;
    const float li = -1.0f + (float)i * step;
    const float lj = -1.0f + (float)j * step;

    const float Ax = 63.5f * (li * R00 + lj * R10 - R20 + 1.0f);
    const float Ay = 63.5f * (li * R01 + lj * R11 - R21 + 1.0f);
    const float Az = 63.5f * (li * R02 + lj * R12 - R22 + 1.0f);

    // analytic valid-k interval: A + k*s in (-1, 128) per axis
    float klo = 0.0f, khi = 127.0f;
    bool empty = false;
    {
        const float a[3] = {Ax, Ay, Az};
        const float s[3] = {R20, R21, R22};
        #pragma unroll
        for (int m = 0; m < 3; ++m) {
            if (fabsf(s[m]) > 1e-6f) {
                const float t0 = (-1.0f  - a[m]) / s[m];
                const float t1 = (128.0f - a[m]) / s[m];
                klo = fmaxf(klo, fminf(t0, t1));
                khi = fminf(khi, fmaxf(t0, t1));
            } else if (a[m] <= -1.0f || a[m] >= 128.0f) {
                empty = true;
            }
        }
    }
    int k_start = (int)ceilf(klo - 1e-3f);
    int k_end   = (int)floorf(khi + 1e-3f);
    if (k_start < 0) k_start = 0;
    if (k_end > 127) k_end = 127;
    if (empty) k_end = k_start - 1;

    const uint2* __restrict__ vol2 = packed + ((size_t)b << 21);

    float acc = 0.0f;
    u4v uA, uB, uC, uD;

    int n = k_end - k_start + 1;
    int k = k_start;
    if (n > 0) {
        // PREP is always address-safe (indices clamped), so over-prefetch ok.
        PREP(A, k); PREP(B, k + 1); PREP(C, k + 2);
        while (n > 0) {
            PREP(D, k + 3);
            CONSUME(A, k);
            PREP(A, k + 4);
            if (n > 1) CONSUME(B, k + 1);
            PREP(B, k + 5);
            if (n > 2) CONSUME(C, k + 2);
            PREP(C, k + 6);
            if (n > 3) CONSUME(D, k + 3);
            k += 4; n -= 4;
        }
    }

    out[(bq << 14) + p] = acc;
}

// ---------------- fallback (R4 path) if ws too small ------------------------
#define FPREP(S, kk) do {                                                     \
    const float kf_ = (float)(kk);                                            \
    const float X_ = fmaf(kf_, R20, Ax);                                      \
    const float Y_ = fmaf(kf_, R21, Ay);                                      \
    const float Z_ = fmaf(kf_, R22, Az);                                      \
    const float xf_ = floorf(X_), yf_ = floorf(Y_), zf_ = floorf(Z_);         \
    const int ix_ = (int)xf_, iy_ = (int)yf_, iz_ = (int)zf_;                 \
    const float fx_ = X_ - xf_, fy_ = Y_ - yf_, fz_ = Z_ - zf_;               \
    const bool vx0_ = (ix_ >= 0)  & (ix_ <= 127);                             \
    const bool vx1_ = (ix_ >= -1) & (ix_ <= 126);                             \
    const bool vy0_ = (iy_ >= 0)  & (iy_ <= 127);                             \
    const bool vy1_ = (iy_ >= -1) & (iy_ <= 126);                             \
    const bool vz0_ = (iz_ >= 0)  & (iz_ <= 127);                             \
    const bool vz1_ = (iz_ >= -1) & (iz_ <= 126);                             \
    const int ex_  = min(max(ix_, 0), 126);                                   \
    s##S##hi = (ix_ > 126);                                                   \
    s##S##lo = (ix_ < 0);                                                     \
    const int cy0_ = min(max(iy_, 0), 127);                                   \
    const int cy1_ = min(max(iy_ + 1, 0), 127);                               \
    const int cz0_ = min(max(iz_, 0), 127);                                   \
    const int cz1_ = min(max(iz_ + 1, 0), 127);                               \
    g##S##x0 = vx0_ ? (1.0f - fx_) : 0.0f;                                    \
    g##S##x1 = vx1_ ? fx_ : 0.0f;                                             \
    g##S##y0 = vy0_ ? (1.0f - fy_) : 0.0f;                                    \
    g##S##y1 = vy1_ ? fy_ : 0.0f;                                             \
    g##S##z0 = vz0_ ? (1.0f - fz_) : 0.0f;                                    \
    g##S##z1 = vz1_ ? fz_ : 0.0f;                                             \
    const int z0o_ = cz0_ << 14, z1o_ = cz1_ << 14;                           \
    const int y0o_ = cy0_ << 7,  y1o_ = cy1_ << 7;                            \
    p##S##a = *(const f2*)(vol + (z0o_ + y0o_ + ex_));                        \
    p##S##b = *(const f2*)(vol + (z0o_ + y1o_ + ex_));                        \
    p##S##c = *(const f2*)(vol + (z1o_ + y0o_ + ex_));                        \
    p##S##d = *(const f2*)(vol + (z1o_ + y1o_ + ex_));                        \
} while (0)

#define FCONSUME(S) do {                                                      \
    const float c000 = s##S##hi ? p##S##a.y : p##S##a.x;                      \
    const float c100 = s##S##lo ? p##S##a.x : p##S##a.y;                      \
    const float c010 = s##S##hi ? p##S##b.y : p##S##b.x;                      \
    const float c110 = s##S##lo ? p##S##b.x : p##S##b.y;                      \
    const float c001 = s##S##hi ? p##S##c.y : p##S##c.x;                      \
    const float c101 = s##S##lo ? p##S##c.x : p##S##c.y;                      \
    const float c011 = s##S##hi ? p##S##d.y : p##S##d.x;                      \
    const float c111 = s##S##lo ? p##S##d.x : p##S##d.y;                      \
    const float s0_ = g##S##y0 * fmaf(g##S##x0, c000, g##S##x1 * c100)        \
                    + g##S##y1 * fmaf(g##S##x0, c010, g##S##x1 * c110);       \
    const float s1_ = g##S##y0 * fmaf(g##S##x0, c001, g##S##x1 * c101)        \
                    + g##S##y1 * fmaf(g##S##x0, c011, g##S##x1 * c111);       \
    acc = fmaf(g##S##z0, s0_, fmaf(g##S##z1, s1_, acc));                      \
} while (0)

__global__ __launch_bounds__(256) void proj_kernel_fallback(
    const float* __restrict__ density,
    const float* __restrict__ rotation,
    float* __restrict__ out)
{
    const int xcd  = blockIdx.x & 7;
    const int slot = blockIdx.x >> 3;
    const int b    = xcd >> 1;
    const int tile = ((xcd & 1) << 8) + slot;
    const int q    = tile >> 6;
    const int blk  = tile & 63;
    const int bq   = (b << 3) + q;

    const int p = (blk << 8) + threadIdx.x;
    const int i = p & (LSZ - 1);
    const int j = p >> 7;

    const float* R = rotation + bq * 9;
    const float R00 = R[0], R01 = R[1], R02 = R[2];
    const float R10 = R[3], R11 = R[4], R12 = R[5];
    const float R20 = R[6], R21 = R[7], R22 = R[8];

    const float step = 2.0f / 127.0f;
    const float li = -1.0f + (float)i * step;
    const float lj = -1.0f + (float)j * step;

    const float Ax = 63.5f * (li * R00 + lj * R10 - R20 + 1.0f);
    const float Ay = 63.5f * (li * R01 + lj * R11 - R21 + 1.0f);
    const float Az = 63.5f * (li * R02 + lj * R12 - R22 + 1.0f);

    float klo = 0.0f, khi = 127.0f;
    bool empty = false;
    {
        const float a[3] = {Ax, Ay, Az};
        const float s[3] = {R20, R21, R22};
        #pragma unroll
        for (int m = 0; m < 3; ++m) {
            if (fabsf(s[m]) > 1e-6f) {
                const float t0 = (-1.0f  - a[m]) / s[m];
                const float t1 = (128.0f - a[m]) / s[m];
                klo = fmaxf(klo, fminf(t0, t1));
                khi = fminf(khi, fmaxf(t0, t1));
            } else if (a[m] <= -1.0f || a[m] >= 128.0f) {
                empty = true;
            }
        }
    }
    int k_start = (int)ceilf(klo - 1e-3f);
    int k_end   = (int)floorf(khi + 1e-3f);
    if (k_start < 0) k_start = 0;
    if (k_end > 127) k_end = 127;
    if (empty) k_end = k_start - 1;

    const float* __restrict__ vol = density + (size_t)b * (LSZ * LSZ * LSZ);

    float acc = 0.0f;
    float gAx0, gAx1, gAy0, gAy1, gAz0, gAz1;
    f2 pAa, pAb, pAc, pAd;
    bool sAhi, sAlo;
    float gBx0, gBx1, gBy0, gBy1, gBz0, gBz1;
    f2 pBa, pBb, pBc, pBd;
    bool sBhi, sBlo;

    int k = k_start;
    if (k <= k_end) {
        FPREP(A, k);
        while (k <= k_end) {
            const int kn = k + 1;
            const bool hasB = (kn <= k_end);
            if (hasB) FPREP(B, kn);
            FCONSUME(A);
            if (hasB) FCONSUME(B);
            k += 2;
            if (k <= k_end) FPREP(A, k);
        }
    }

    out[(bq << 14) + p] = acc;
}

extern "C" void kernel_launch(void* const* d_in, const int* in_sizes, int n_in,
                              void* d_out, int out_size, void* d_ws, size_t ws_size,
                              hipStream_t stream) {
    const float* density  = (const float*)d_in[0];
    const float* rotation = (const float*)d_in[1];
    float* out = (float*)d_out;

    if (ws_size >= PACKED_BYTES) {
        uint2* packed = (uint2*)d_ws;
        pack_kernel<<<4 * 128 * 128, 128, 0, stream>>>(density, packed);
        proj_kernel_packed<<<2048, 256, 0, stream>>>(packed, rotation, out);
    } else {
        proj_kernel_fallback<<<2048, 256, 0, stream>>>(density, rotation, out);
    }
}

// Round 7
// 207.590 us; speedup vs baseline: 2.6537x; 1.0502x over previous
//
#include <hip/hip_runtime.h>

// SpatialGridProjector: out[b,q,j,i] = sum_k trilinear(density[b], P(i,j,k))
// X(k) = Ax + k*R20, Y(k) = Ay + k*R21, Z(k) = Az + k*R22  (voxel coords)
// grid_sample(align_corners=True, zero padding).
//
// R6 vs R5 (R5: corner-packed bf16 volume, 1x16B gather/step, 218us total):
//  - proj kernel was VALU-issue bound (~60 VALU/step). Split the ray into
//    boundary (safe, clamped+selects) and INTERIOR (pos in [0,126.95] on all
//    axes -> all corners valid -> no clamps/selects; fx/fy/fz carried in
//    stage regs). Over-prefetch safety via min(k+off, d).
//  - pack kernel vectorized 4x (float4 row loads, uint4 stores).

#define LSZ 128
#define PACKED_BYTES ((size_t)4 * 128 * 128 * 128 * 8)  // 64 MiB

typedef float f2 __attribute__((ext_vector_type(2), aligned(4)));
typedef unsigned int u4v __attribute__((ext_vector_type(4), aligned(8)));

__device__ __forceinline__ float bl(unsigned int d) {
    return __uint_as_float(d << 16);
}
__device__ __forceinline__ float bh(unsigned int d) {
    return __uint_as_float(d & 0xffff0000u);
}
__device__ __forceinline__ unsigned int pk2(float lo, float hi) {
    unsigned int ul = __float_as_uint(lo), uh = __float_as_uint(hi);
    ul = (ul + 0x7fffu + ((ul >> 16) & 1u)) >> 16;   // RNE bf16
    uh = (uh + 0x7fffu + ((uh >> 16) & 1u)) >> 16;
    return ul | (uh << 16);
}

// ---------------- pack kernel: f32 volume -> corner-packed bf16 -------------
// entry (z,y,x): dword0 = bf16{ v(z,y,x), v(z,y+1,x) }
//                dword1 = bf16{ v(z+1,y,x), v(z+1,y+1,x) }
__global__ __launch_bounds__(256) void pack_kernel(
    const float* __restrict__ density, uint2* __restrict__ packed)
{
    const int t  = blockIdx.x * 256 + threadIdx.x;
    const int xq = (t & 31) << 2;          // x quad base
    const int y  = (t >> 5) & 127;
    const int z  = (t >> 12) & 127;
    const int b  = t >> 19;
    const float* __restrict__ v = density + ((size_t)b << 21);
    const int y1 = min(y + 1, 127), z1 = min(z + 1, 127);
    const float4 a0 = *(const float4*)(v + (z  << 14) + (y  << 7) + xq);
    const float4 a1 = *(const float4*)(v + (z  << 14) + (y1 << 7) + xq);
    const float4 c0 = *(const float4*)(v + (z1 << 14) + (y  << 7) + xq);
    const float4 c1 = *(const float4*)(v + (z1 << 14) + (y1 << 7) + xq);
    uint4 o0, o1;
    o0.x = pk2(a0.x, a1.x); o0.y = pk2(c0.x, c1.x);
    o0.z = pk2(a0.y, a1.y); o0.w = pk2(c0.y, c1.y);
    o1.x = pk2(a0.z, a1.z); o1.y = pk2(c0.z, c1.z);
    o1.z = pk2(a0.w, a1.w); o1.w = pk2(c0.w, c1.w);
    uint4* dst = (uint4*)(packed + ((size_t)b << 21) + (z << 14) + (y << 7) + xq);
    dst[0] = o0; dst[1] = o1;
}

// ---------------- interior fast path (all corners valid) --------------------
#define FPREPI(S, kk) do {                                                    \
    const float kf_ = (float)min((kk), d);                                    \
    const float X_ = fmaf(kf_, R20, Ax);                                      \
    const float Y_ = fmaf(kf_, R21, Ay);                                      \
    const float Z_ = fmaf(kf_, R22, Az);                                      \
    const int ix_ = (int)X_;                                                  \
    const int iy_ = (int)Y_;                                                  \
    const int iz_ = (int)Z_;                                                  \
    fx##S = X_ - (float)ix_;                                                  \
    fy##S = Y_ - (float)iy_;                                                  \
    fz##S = Z_ - (float)iz_;                                                  \
    u##S = *(const u4v*)(vol2 + ((iz_ << 14) + (iy_ << 7) + ix_));            \
} while (0)

#define FCONSI(S) do {                                                        \
    const float gx0 = 1.0f - fx##S;                                           \
    const float gy0 = 1.0f - fy##S;                                           \
    const float gz0 = 1.0f - fz##S;                                           \
    const float c000 = bl(u##S.x), c010 = bh(u##S.x);                         \
    const float c001 = bl(u##S.y), c011 = bh(u##S.y);                         \
    const float c100 = bl(u##S.z), c110 = bh(u##S.z);                         \
    const float c101 = bl(u##S.w), c111 = bh(u##S.w);                         \
    const float s0_ = gy0   * fmaf(gx0, c000, fx##S * c100)                   \
                    + fy##S * fmaf(gx0, c010, fx##S * c110);                  \
    const float s1_ = gy0   * fmaf(gx0, c001, fx##S * c101)                   \
                    + fy##S * fmaf(gx0, c011, fx##S * c111);                  \
    acc = fmaf(gz0, s0_, fmaf(fz##S, s1_, acc));                              \
} while (0)

// ---------------- boundary safe path (clamped + per-corner selects) ---------
#define SPREP(S, kk) do {                                                     \
    const float kf_ = (float)(kk);                                            \
    const float X_ = fmaf(kf_, R20, Ax);                                      \
    const float Y_ = fmaf(kf_, R21, Ay);                                      \
    const float Z_ = fmaf(kf_, R22, Az);                                      \
    const int ix_ = (int)floorf(X_);                                          \
    const int iy_ = (int)floorf(Y_);                                          \
    const int iz_ = (int)floorf(Z_);                                          \
    const int ex_ = min(max(ix_, 0), 126);                                    \
    const int ey_ = min(max(iy_, 0), 126);                                    \
    const int ez_ = min(max(iz_, 0), 126);                                    \
    u##S = *(const u4v*)(vol2 + ((ez_ << 14) + (ey_ << 7) + ex_));            \
} while (0)

#define SCONS(S, kk) do {                                                     \
    const float kf_ = (float)(kk);                                            \
    const float X_ = fmaf(kf_, R20, Ax);                                      \
    const float Y_ = fmaf(kf_, R21, Ay);                                      \
    const float Z_ = fmaf(kf_, R22, Az);                                      \
    const float xf_ = floorf(X_), yf_ = floorf(Y_), zf_ = floorf(Z_);         \
    const int ix_ = (int)xf_, iy_ = (int)yf_, iz_ = (int)zf_;                 \
    const float fx_ = X_ - xf_, fy_ = Y_ - yf_, fz_ = Z_ - zf_;               \
    const bool vx0_ = (ix_ >= 0)  & (ix_ <= 127);                             \
    const bool vx1_ = (ix_ >= -1) & (ix_ <= 126);                             \
    const bool vy0_ = (iy_ >= 0)  & (iy_ <= 127);                             \
    const bool vy1_ = (iy_ >= -1) & (iy_ <= 126);                             \
    const bool vz0_ = (iz_ >= 0)  & (iz_ <= 127);                             \
    const bool vz1_ = (iz_ >= -1) & (iz_ <= 126);                             \
    const float gx0 = vx0_ ? (1.0f - fx_) : 0.0f;                             \
    const float gx1 = vx1_ ? fx_ : 0.0f;                                      \
    const float gy0 = vy0_ ? (1.0f - fy_) : 0.0f;                             \
    const float gy1 = vy1_ ? fy_ : 0.0f;                                      \
    const float gz0 = vz0_ ? (1.0f - fz_) : 0.0f;                             \
    const float gz1 = vz1_ ? fz_ : 0.0f;                                      \
    const bool xhi_ = (ix_ > 126), xlo_ = (ix_ < 0);                          \
    const bool yhi_ = (iy_ > 126), ylo_ = (iy_ < 0);                          \
    const bool zhi_ = (iz_ > 126), zlo_ = (iz_ < 0);                          \
    const unsigned int a0z0 = xhi_ ? u##S.z : u##S.x;                         \
    const unsigned int a0z1 = xhi_ ? u##S.w : u##S.y;                         \
    const unsigned int a1z0 = xlo_ ? u##S.x : u##S.z;                         \
    const unsigned int a1z1 = xlo_ ? u##S.y : u##S.w;                         \
    const unsigned int dA = zhi_ ? a0z1 : a0z0;                               \
    const unsigned int dB = zlo_ ? a0z0 : a0z1;                               \
    const unsigned int dC = zhi_ ? a1z1 : a1z0;                               \
    const unsigned int dD = zlo_ ? a1z0 : a1z1;                               \
    const float c000 = yhi_ ? bh(dA) : bl(dA);                                \
    const float c010 = ylo_ ? bl(dA) : bh(dA);                                \
    const float c100 = yhi_ ? bh(dC) : bl(dC);                                \
    const float c110 = ylo_ ? bl(dC) : bh(dC);                                \
    const float c001 = yhi_ ? bh(dB) : bl(dB);                                \
    const float c011 = ylo_ ? bl(dB) : bh(dB);                                \
    const float c101 = yhi_ ? bh(dD) : bl(dD);                                \
    const float c111 = ylo_ ? bl(dD) : bh(dD);                                \
    const float s0_ = gy0 * fmaf(gx0, c000, gx1 * c100)                       \
                    + gy1 * fmaf(gx0, c010, gx1 * c110);                      \
    const float s1_ = gy0 * fmaf(gx0, c001, gx1 * c101)                       \
                    + gy1 * fmaf(gx0, c011, gx1 * c111);                      \
    acc = fmaf(gz0, s0_, fmaf(gz1, s1_, acc));                                \
} while (0)

__global__ __launch_bounds__(256) void proj_kernel_packed(
    const uint2* __restrict__ packed,    // (B, L, L, L) corner-packed bf16
    const float* __restrict__ rotation,  // (B, Q, 3, 3)
    float* __restrict__ out)             // (B, Q, L, L)
{
    // XCD-aware swizzle: volume b -> XCDs {2b, 2b+1} (blockIdx % 8 ~ XCD).
    const int xcd  = blockIdx.x & 7;
    const int slot = blockIdx.x >> 3;
    const int b    = xcd >> 1;
    const int tile = ((xcd & 1) << 8) + slot;
    const int q    = tile >> 6;
    const int blk  = tile & 63;
    const int bq   = (b << 3) + q;

    const int p = (blk << 8) + threadIdx.x;
    const int i = p & (LSZ - 1);
    const int j = p >> 7;

    const float* R = rotation + bq * 9;
    const float R00 = R[0], R01 = R[1], R02 = R[2];
    const float R10 = R[3], R11 = R[4], R12 = R[5];
    const float R20 = R[6], R21 = R[7], R22 = R[8];

    const float step = 2.0f / 127.0f;
    const float li = -1.0f + (float)i * step;
    const float lj = -1.0f + (float)j * step;

    const float Ax = 63.5f * (li * R00 + lj * R10 - R20 + 1.0f);
    const float Ay = 63.5f * (li * R01 + lj * R11 - R21 + 1.0f);
    const float Az = 63.5f * (li * R02 + lj * R12 - R22 + 1.0f);

    // outer interval: A + k*s in (-1, 128) per axis
    float klo = 0.0f, khi = 127.0f;
    // interior interval: A + k*s in [0, 126.95] per axis (all corners valid)
    float klo2 = 0.0f, khi2 = 127.0f;
    bool empty = false, empty2 = false;
    {
        const float a_[3] = {Ax, Ay, Az};
        const float s_[3] = {R20, R21, R22};
        #pragma unroll
        for (int m = 0; m < 3; ++m) {
            if (fabsf(s_[m]) > 1e-6f) {
                const float r = 1.0f / s_[m];
                const float t0 = (-1.0f   - a_[m]) * r;
                const float t1 = (128.0f  - a_[m]) * r;
                klo = fmaxf(klo, fminf(t0, t1));
                khi = fminf(khi, fmaxf(t0, t1));
                const float w0 = (0.0f    - a_[m]) * r;
                const float w1 = (126.95f - a_[m]) * r;
                klo2 = fmaxf(klo2, fminf(w0, w1));
                khi2 = fminf(khi2, fmaxf(w0, w1));
            } else {
                if (a_[m] <= -1.0f   || a_[m] >= 128.0f)   empty  = true;
                if (a_[m] <  0.001f  || a_[m] >  126.94f)  empty2 = true;
            }
        }
    }
    int a = (int)ceilf(klo - 1e-3f);
    int bnd = (int)floorf(khi + 1e-3f);
    if (a < 0) a = 0;
    if (bnd > 127) bnd = 127;
    if (empty) bnd = a - 1;

    int c = (int)ceilf(klo2 + 0.05f);
    int d = (int)floorf(khi2 - 0.05f);
    if (c < a) c = a;
    if (d > bnd) d = bnd;
    if (empty2 || d < c) { c = bnd + 1; d = bnd; }

    const uint2* __restrict__ vol2 = packed + ((size_t)b << 21);

    float acc = 0.0f;
    u4v uA, uB, uC, uD;
    float fxA, fyA, fzA, fxB, fyB, fzB, fxC, fyC, fzC, fxD, fyD, fzD;

    // ---- boundary head: [a, c-1], 2-stage safe pipeline ----
    {
        int k = a;
        const int e = c - 1;
        if (k <= e) {
            SPREP(A, k);
            while (k <= e) {
                const int kn = k + 1;
                const bool hasB = (kn <= e);
                if (hasB) SPREP(B, kn);
                SCONS(A, k);
                if (hasB) SCONS(B, kn);
                k += 2;
                if (k <= e) SPREP(A, k);
            }
        }
    }

    // ---- interior: [c, d], 4-stage fast pipeline (no clamps/selects) ----
    {
        int n = d - c + 1;
        int k = c;
        if (n > 0) {
            FPREPI(A, k); FPREPI(B, k + 1); FPREPI(C, k + 2);
            while (n > 0) {
                FPREPI(D, k + 3);
                FCONSI(A);
                FPREPI(A, k + 4);
                if (n > 1) FCONSI(B);
                FPREPI(B, k + 5);
                if (n > 2) FCONSI(C);
                FPREPI(C, k + 6);
                if (n > 3) FCONSI(D);
                k += 4; n -= 4;
            }
        }
    }

    // ---- boundary tail: [d+1, bnd], 2-stage safe pipeline ----
    {
        int k = d + 1;
        const int e = bnd;
        if (k <= e) {
            SPREP(A, k);
            while (k <= e) {
                const int kn = k + 1;
                const bool hasB = (kn <= e);
                if (hasB) SPREP(B, kn);
                SCONS(A, k);
                if (hasB) SCONS(B, kn);
                k += 2;
                if (k <= e) SPREP(A, k);
            }
        }
    }

    out[(bq << 14) + p] = acc;
}

// ---------------- fallback (R4-style, f32 pair loads) if ws too small -------
__global__ __launch_bounds__(256) void proj_kernel_fallback(
    const float* __restrict__ density,
    const float* __restrict__ rotation,
    float* __restrict__ out)
{
    const int xcd  = blockIdx.x & 7;
    const int slot = blockIdx.x >> 3;
    const int b    = xcd >> 1;
    const int tile = ((xcd & 1) << 8) + slot;
    const int q    = tile >> 6;
    const int blk  = tile & 63;
    const int bq   = (b << 3) + q;

    const int p = (blk << 8) + threadIdx.x;
    const int i = p & (LSZ - 1);
    const int j = p >> 7;

    const float* R = rotation + bq * 9;
    const float R00 = R[0], R01 = R[1], R02 = R[2];
    const float R10 = R[3], R11 = R[4], R12 = R[5];
    const float R20 = R[6], R21 = R[7], R22 = R[8];

    const float step = 2.0f / 127.0f;
    const float li = -1.0f + (float)i * step;
    const float lj = -1.0f + (float)j * step;

    const float Ax = 63.5f * (li * R00 + lj * R10 - R20 + 1.0f);
    const float Ay = 63.5f * (li * R01 + lj * R11 - R21 + 1.0f);
    const float Az = 63.5f * (li * R02 + lj * R12 - R22 + 1.0f);

    float klo = 0.0f, khi = 127.0f;
    bool empty = false;
    {
        const float a_[3] = {Ax, Ay, Az};
        const float s_[3] = {R20, R21, R22};
        #pragma unroll
        for (int m = 0; m < 3; ++m) {
            if (fabsf(s_[m]) > 1e-6f) {
                const float t0 = (-1.0f  - a_[m]) / s_[m];
                const float t1 = (128.0f - a_[m]) / s_[m];
                klo = fmaxf(klo, fminf(t0, t1));
                khi = fminf(khi, fmaxf(t0, t1));
            } else if (a_[m] <= -1.0f || a_[m] >= 128.0f) {
                empty = true;
            }
        }
    }
    int k_start = (int)ceilf(klo - 1e-3f);
    int k_end   = (int)floorf(khi + 1e-3f);
    if (k_start < 0) k_start = 0;
    if (k_end > 127) k_end = 127;
    if (empty) k_end = k_start - 1;

    const float* __restrict__ vol = density + (size_t)b * (LSZ * LSZ * LSZ);

    float acc = 0.0f;
    for (int k = k_start; k <= k_end; ++k) {
        const float kf = (float)k;
        const float X = fmaf(kf, R20, Ax);
        const float Y = fmaf(kf, R21, Ay);
        const float Z = fmaf(kf, R22, Az);
        const float xf = floorf(X), yf = floorf(Y), zf = floorf(Z);
        const int ix = (int)xf, iy = (int)yf, iz = (int)zf;
        const float fx = X - xf, fy = Y - yf, fz = Z - zf;
        const bool vx0 = (ix >= 0)  & (ix <= 127);
        const bool vx1 = (ix >= -1) & (ix <= 126);
        const bool vy0 = (iy >= 0)  & (iy <= 127);
        const bool vy1 = (iy >= -1) & (iy <= 126);
        const bool vz0 = (iz >= 0)  & (iz <= 127);
        const bool vz1 = (iz >= -1) & (iz <= 126);
        const int cx0 = min(max(ix, 0), 127);
        const int cx1 = min(max(ix + 1, 0), 127);
        const int cy0 = min(max(iy, 0), 127);
        const int cy1 = min(max(iy + 1, 0), 127);
        const int cz0 = min(max(iz, 0), 127);
        const int cz1 = min(max(iz + 1, 0), 127);
        const float gx0 = vx0 ? (1.0f - fx) : 0.0f;
        const float gx1 = vx1 ? fx : 0.0f;
        const float gy0 = vy0 ? (1.0f - fy) : 0.0f;
        const float gy1 = vy1 ? fy : 0.0f;
        const float gz0 = vz0 ? (1.0f - fz) : 0.0f;
        const float gz1 = vz1 ? fz : 0.0f;
        const int z0o = cz0 << 14, z1o = cz1 << 14;
        const int y0o = cy0 << 7,  y1o = cy1 << 7;
        const float v000 = vol[z0o + y0o + cx0];
        const float v100 = vol[z0o + y0o + cx1];
        const float v010 = vol[z0o + y1o + cx0];
        const float v110 = vol[z0o + y1o + cx1];
        const float v001 = vol[z1o + y0o + cx0];
        const float v101 = vol[z1o + y0o + cx1];
        const float v011 = vol[z1o + y1o + cx0];
        const float v111 = vol[z1o + y1o + cx1];
        const float s0 = gy0 * fmaf(gx0, v000, gx1 * v100)
                       + gy1 * fmaf(gx0, v010, gx1 * v110);
        const float s1 = gy0 * fmaf(gx0, v001, gx1 * v101)
                       + gy1 * fmaf(gx0, v011, gx1 * v111);
        acc = fmaf(gz0, s0, fmaf(gz1, s1, acc));
    }

    out[(bq << 14) + p] = acc;
}

extern "C" void kernel_launch(void* const* d_in, const int* in_sizes, int n_in,
                              void* d_out, int out_size, void* d_ws, size_t ws_size,
                              hipStream_t stream) {
    const float* density  = (const float*)d_in[0];
    const float* rotation = (const float*)d_in[1];
    float* out = (float*)d_out;

    if (ws_size >= PACKED_BYTES) {
        uint2* packed = (uint2*)d_ws;
        pack_kernel<<<8192, 256, 0, stream>>>(density, packed);
        proj_kernel_packed<<<2048, 256, 0, stream>>>(packed, rotation, out);
    } else {
        proj_kernel_fallback<<<2048, 256, 0, stream>>>(density, rotation, out);
    }
}